// Round 10
// baseline (193.039 us; speedup 1.0000x reference)
//
#include <hip/hip_runtime.h>
#include <hip/hip_bf16.h>

// Problem constants: T=1024, B=2, E=1024, H=16, D=64, R=2*T-1
#define TT 1024
#define BB 2
#define EE 1024
#define HH 16
#define DD 64
#define RR 2047
#define TB (TT * BB)   // 2048
#define E3 (3 * EE)    // 3072

typedef __attribute__((ext_vector_type(4))) float f32x4;
typedef __attribute__((ext_vector_type(8))) short s16x8;

static __device__ __forceinline__ short f2bf(float x) {
  unsigned u = __builtin_bit_cast(unsigned, x);
  unsigned r = (u + 0x7FFFu + ((u >> 16) & 1u)) >> 16;
  return (short)r;
}
static __device__ __forceinline__ float bf2f(short x) {
  unsigned u = ((unsigned)(unsigned short)x) << 16;
  return __builtin_bit_cast(float, u);
}
static __device__ __forceinline__ float bperm(int idx, float v) {
  return __builtin_bit_cast(float,
      __builtin_amdgcn_ds_bpermute(idx, __builtin_bit_cast(int, v)));
}

// ---------------------------------------------------------------------------
// Fused fp32 -> bf16 convert for all 5 tensors (one launch).
// ---------------------------------------------------------------------------
__global__ __launch_bounds__(256) void cvt_all(
    const float* __restrict__ x, const float* __restrict__ in_w,
    const float* __restrict__ pos, const float* __restrict__ pos_w,
    const float* __restrict__ out_w,
    short* __restrict__ xb, short* __restrict__ inwb, short* __restrict__ posb,
    short* __restrict__ poswb, short* __restrict__ outwb) {
  const long M1 = 1 << 20;
  long off = (long)(blockIdx.x * 256 + threadIdx.x) * 8;
  const float* src; short* dst; long nsrc;
  if (off < 2 * M1)      { src = x;     dst = xb;    nsrc = 2 * M1; }
  else if (off < 5 * M1) { off -= 2 * M1; src = in_w;  dst = inwb;  nsrc = 3 * M1; }
  else if (off < 7 * M1) { off -= 5 * M1; src = pos;   dst = posb;  nsrc = (long)RR * EE; }
  else if (off < 8 * M1) { off -= 7 * M1; src = pos_w; dst = poswb; nsrc = M1; }
  else                   { off -= 8 * M1; src = out_w; dst = outwb; nsrc = M1; }
  s16x8 o;
  if (off + 8 <= nsrc) {
    f32x4 a = *(const f32x4*)&src[off];
    f32x4 c = *(const f32x4*)&src[off + 4];
    #pragma unroll
    for (int j = 0; j < 4; ++j) { o[j] = f2bf(a[j]); o[4 + j] = f2bf(c[j]); }
  } else {
    #pragma unroll
    for (int j = 0; j < 8; ++j) o[j] = 0;
  }
  *(s16x8*)&dst[off] = o;
}

// ---------------------------------------------------------------------------
// bf16 MFMA GEMM (m97 structure): C[M,N] = A[M,K] @ W[N,K]^T + bias[N]
// ---------------------------------------------------------------------------
#define GBM 128
#define GBN 128
#define GBK 32

template <int OUT_BF16>
__global__ __launch_bounds__(256) void gemm_bf16_mfma(
    const short* __restrict__ A, const short* __restrict__ W,
    const float* __restrict__ bias, void* __restrict__ Cout,
    int M, int N, int K) {
  __shared__ __align__(16) short lA[2][GBM * GBK];
  __shared__ __align__(16) short lB[2][GBN * GBK];

  const int tid = threadIdx.x;
  const int lane = tid & 63;
  const int wv = tid >> 6;
  const int g = lane >> 4, cc = lane & 15;
  const int wr = wv >> 1, wc = wv & 1;
  const int m0 = blockIdx.y * GBM, n0 = blockIdx.x * GBN;

  f32x4 acc[4][4];
  #pragma unroll
  for (int i = 0; i < 4; ++i)
    #pragma unroll
    for (int j = 0; j < 4; ++j) acc[i][j] = (f32x4){0.f, 0.f, 0.f, 0.f};

#define STAGE_TILE(kk_, buf_)                                                  \
  {                                                                            \
    _Pragma("unroll")                                                          \
    for (int s = 0; s < 2; ++s) {                                              \
      int c = s * 256 + tid;                                                   \
      int row = c >> 2, slot = c & 3;                                          \
      int k8 = slot ^ (row & 3);                                               \
      __builtin_amdgcn_global_load_lds(                                        \
          (const __attribute__((address_space(1))) void*)(A + (size_t)(m0 + row) * K + (kk_) + k8 * 8), \
          (__attribute__((address_space(3))) void*)&lA[buf_][c * 8], 16, 0, 0);\
      __builtin_amdgcn_global_load_lds(                                        \
          (const __attribute__((address_space(1))) void*)(W + (size_t)(n0 + row) * K + (kk_) + k8 * 8), \
          (__attribute__((address_space(3))) void*)&lB[buf_][c * 8], 16, 0, 0);\
    }                                                                          \
  }

  int cur = 0;
  const int nt = K / GBK;
  STAGE_TILE(0, 0);

  #pragma unroll 1
  for (int t = 0; t < nt; ++t) {
    __syncthreads();
    if (t + 1 < nt) STAGE_TILE((t + 1) * GBK, cur ^ 1);

    s16x8 af[4], bf[4];
    #pragma unroll
    for (int mt = 0; mt < 4; ++mt) {
      int row = 64 * wr + 16 * mt + cc;
      af[mt] = *(const s16x8*)&lA[cur][row * GBK + ((g ^ (row & 3)) * 8)];
    }
    #pragma unroll
    for (int ntc = 0; ntc < 4; ++ntc) {
      int col = 64 * wc + 16 * ntc + cc;
      bf[ntc] = *(const s16x8*)&lB[cur][col * GBK + ((g ^ (col & 3)) * 8)];
    }
    #pragma unroll
    for (int mt = 0; mt < 4; ++mt)
      #pragma unroll
      for (int ntc = 0; ntc < 4; ++ntc)
        acc[mt][ntc] = __builtin_amdgcn_mfma_f32_16x16x32_bf16(
            af[mt], bf[ntc], acc[mt][ntc], 0, 0, 0);
    cur ^= 1;
  }
#undef STAGE_TILE

  #pragma unroll
  for (int ntc = 0; ntc < 4; ++ntc) {
    int col = n0 + 64 * wc + 16 * ntc + cc;
    float bv = bias[col];
    #pragma unroll
    for (int mt = 0; mt < 4; ++mt)
      #pragma unroll
      for (int r = 0; r < 4; ++r) {
        int rowg = m0 + 64 * wr + 16 * mt + 4 * g + r;
        float val = acc[mt][ntc][r] + bv;
        if (OUT_BF16)
          ((short*)Cout)[(size_t)rowg * N + col] = f2bf(val);
        else
          ((float*)Cout)[(size_t)rowg * N + col] = val;
      }
  }
}

// ---------------------------------------------------------------------------
// V transpose: qkvb V-part [key][(h,d)] -> vT [bh][d][key]   (bf16, 4 MB)
// grid (T/64=16, B*H=32), 256 thr. LDS 64x64 tile (+pad 72 rows for align).
// ---------------------------------------------------------------------------
__global__ __launch_bounds__(256) void transpose_v(
    const short* __restrict__ qkvb, short* __restrict__ vT) {
  __shared__ short tile[64][72];
  const int tid = threadIdx.x;
  const int kt = blockIdx.x;
  const int bh = blockIdx.y;
  const int b = bh >> 4, h = bh & 15;
  const int j = tid >> 2;           // 0..63 local key
  const int cg = (tid & 3) * 16;    // d group
  const short* src = qkvb + (size_t)((kt * 64 + j) * BB + b) * E3 + 2 * EE + h * DD + cg;
  *(s16x8*)&tile[j][cg]     = *(const s16x8*)src;
  *(s16x8*)&tile[j][cg + 8] = *(const s16x8*)(src + 8);
  __syncthreads();
  short* dst = vT + (size_t)(bh * DD + j) * TT + kt * 64 + cg;
  s16x8 o0, o1;
  #pragma unroll
  for (int m = 0; m < 8; ++m) { o0[m] = tile[cg + m][j]; o1[m] = tile[cg + 8 + m][j]; }
  *(s16x8*)dst       = o0;
  *(s16x8*)(dst + 8) = o1;
}

// ---------------------------------------------------------------------------
// MFMA flash attention — DS-pipe-lean version.
//   Structure = R9 (grid (32,32), 4 waves = (qh,kh), q-co-location, merge).
//   Changes vs R9 (which was ~89 DS ops/wave-iter):
//   1. V^T fragments from pre-transposed global vT (4x16B gathers, VMEM) —
//      no V LDS staging, no 32 scalar ds_reads.           (-36 DS ops)
//   2. Exact defer-max softmax: rescale branch only when __any(mx>mrun)
//      (bit-exact: skipped iters have f=exp(0)=1 in exact online softmax);
//      l kept as PER-LANE partial (lpart = lpart*f + sum P), cross-lane
//      sum reduce hoisted to after the loop.              (-32 DS ops common)
//   3. bperm BD gather (12) + sPm round-trip (9) kept.
//   score[i,j] = qw_i.k_j + qr_i.p[j-i+1023]  (1/8 scale folded in)
// LDS arena (23040 B): sO[w]=arena+w*4352 (merge only);
//   sPm[w]=arena+17408+w*1280; sML=arena+22528.
// ---------------------------------------------------------------------------
__global__ __launch_bounds__(256, 4) void rel_attn_mfma7(
    const short* __restrict__ qkvb,  // [TB][3E] bf16
    const short* __restrict__ pb,    // [2048][E] bf16 (row 2047 zeroed)
    const short* __restrict__ vT,    // [BH][64][1024] bf16
    const float* __restrict__ rwb,   // [H*D]
    const float* __restrict__ rrb,   // [H*D]
    short* __restrict__ ctxb) {      // [TB][E] bf16
  __shared__ __align__(16) char arena[23040];

  const int tid = threadIdx.x;
  const int wv = tid >> 6;
  const int qh = wv >> 1, kh2 = wv & 1;
  const int lane = tid & 63;
  const int g = lane >> 4;      // 0..3
  const int cc = lane & 15;     // 0..15
  const int iq0 = blockIdx.x * 32 + qh * 16;
  const int bh = blockIdx.y;
  const int b = bh >> 4, h = bh & 15;
  const int hoff = h * DD;

  short* sPm = (short*)(arena + 17408 + wv * 1280);    // [16][40]

  // ---- Q fragments: row = cc (q row iq0+cc), k-pack d = 32*kh + 8*g ----
  s16x8 qw[2], qr[2];
  #pragma unroll
  for (int kh = 0; kh < 2; ++kh) {
    const int d0 = 32 * kh + 8 * g;
    const short* qp = qkvb + (size_t)((iq0 + cc) * BB + b) * E3 + hoff + d0;
    const float* rw = rwb + hoff + d0;
    const float* rr = rrb + hoff + d0;
    s16x8 qv = *(const s16x8*)qp;
    #pragma unroll
    for (int j = 0; j < 8; ++j) {
      float q = bf2f(qv[j]);
      qw[kh][j] = f2bf((q + rw[j]) * 0.125f);
      qr[kh][j] = f2bf((q + rr[j]) * 0.125f);
    }
  }

  f32x4 O[4];
  #pragma unroll
  for (int dt = 0; dt < 4; ++dt) O[dt] = (f32x4){0.f, 0.f, 0.f, 0.f};
  float mrun[4], lpart[4];
  #pragma unroll
  for (int r = 0; r < 4; ++r) { mrun[r] = -1e30f; lpart[r] = 0.f; }

  const short* vTbh = vT + (size_t)bh * DD * TT;

  #pragma unroll 1
  for (int t = 0; t < 16; ++t) {
    const int j0 = 512 * kh2 + 32 * t;   // this wave's key tile base

    // ---- K fragments (B-op, contract over d): 16B gathers ----
    s16x8 kf[2][2];
    #pragma unroll
    for (int ct = 0; ct < 2; ++ct)
      #pragma unroll
      for (int kh = 0; kh < 2; ++kh)
        kf[ct][kh] = *(const s16x8*)(qkvb + (size_t)((j0 + 16 * ct + cc) * BB + b) * E3 + EE + hoff + 32 * kh + 8 * g);

    // ---- V^T fragments (B-op for PV, contract over key): 16B gathers ----
    s16x8 vf[4];
    #pragma unroll
    for (int dt = 0; dt < 4; ++dt)
      vf[dt] = *(const s16x8*)(vTbh + (size_t)(16 * dt + cc) * TT + j0 + 8 * g);

    // ---- AC: S[ct] = qw . K^T ----
    f32x4 S[2];
    #pragma unroll
    for (int ct = 0; ct < 2; ++ct) {
      S[ct] = (f32x4){0.f, 0.f, 0.f, 0.f};
      #pragma unroll
      for (int kh = 0; kh < 2; ++kh)
        S[ct] = __builtin_amdgcn_mfma_f32_16x16x32_bf16(qw[kh], kf[ct][kh], S[ct], 0, 0, 0);
    }

    // ---- BD: Btilde = qr . pband^T (3 ut tiles) ----
    const int gmin = j0 - iq0 + 1008;
    f32x4 bt[3];
    #pragma unroll
    for (int ut = 0; ut < 3; ++ut) {
      const int prl = gmin + 16 * ut + cc;   // in [0, 2047]; row 2047 zeroed
      bt[ut] = (f32x4){0.f, 0.f, 0.f, 0.f};
      #pragma unroll
      for (int kh = 0; kh < 2; ++kh) {
        s16x8 pf = *(const s16x8*)(pb + (size_t)prl * EE + hoff + 32 * kh + 8 * g);
        bt[ut] = __builtin_amdgcn_mfma_f32_16x16x32_bf16(qr[kh], pf, bt[ut], 0, 0, 0);
      }
    }
    // gather: S[ct][r] += Btilde[ii=4g+r][16ct + cc+15-ii] via bpermute.
    #pragma unroll
    for (int r = 0; r < 4; ++r) {
      const int usub = cc + 15 - 4 * g - r;            // 0..30
      const int idx = ((lane & 48) | (usub & 15)) << 2;
      const float va = bperm(idx, bt[0][r]);
      const float vb = bperm(idx, bt[1][r]);
      const float vc = bperm(idx, bt[2][r]);
      const bool hi = usub >= 16;
      S[0][r] += hi ? vb : va;
      S[1][r] += hi ? vc : vb;
    }

    // ---- defer-max online softmax (exact) ----
    float mx[4];
    #pragma unroll
    for (int r = 0; r < 4; ++r) mx[r] = fmaxf(S[0][r], S[1][r]);
    const bool need = (mx[0] > mrun[0]) || (mx[1] > mrun[1]) ||
                      (mx[2] > mrun[2]) || (mx[3] > mrun[3]);
    if (__any(need)) {
      // full 16-lane max reduce + rescale (rare; always at t=0)
      #pragma unroll
      for (int msk = 1; msk < 16; msk <<= 1)
        #pragma unroll
        for (int r = 0; r < 4; ++r) mx[r] = fmaxf(mx[r], __shfl_xor(mx[r], msk, 64));
      #pragma unroll
      for (int r = 0; r < 4; ++r) {
        const float mn = fmaxf(mrun[r], mx[r]);
        const float f = __expf(mrun[r] - mn);
        mrun[r] = mn;
        lpart[r] *= f;
        #pragma unroll
        for (int dt = 0; dt < 4; ++dt) O[dt][r] *= f;
      }
    }
    #pragma unroll
    for (int r = 0; r < 4; ++r) {
      S[0][r] = __expf(S[0][r] - mrun[r]);
      S[1][r] = __expf(S[1][r] - mrun[r]);
      lpart[r] += S[0][r] + S[1][r];     // per-lane partial; reduced after loop
    }

    // ---- P to A-fragment layout via wave-private LDS ----
    #pragma unroll
    for (int ct = 0; ct < 2; ++ct)
      #pragma unroll
      for (int r = 0; r < 4; ++r)
        sPm[(4 * g + r) * 40 + 16 * ct + cc] = f2bf(S[ct][r]);

    s16x8 pa = *(const s16x8*)&sPm[cc * 40 + 8 * g];

    // ---- PV ----
    #pragma unroll
    for (int dt = 0; dt < 4; ++dt)
      O[dt] = __builtin_amdgcn_mfma_f32_16x16x32_bf16(pa, vf[dt], O[dt], 0, 0, 0);
  }

  // ---- final 16-lane sum reduce of lpart (once) ----
  #pragma unroll
  for (int msk = 1; msk < 16; msk <<= 1)
    #pragma unroll
    for (int r = 0; r < 4; ++r) lpart[r] += __shfl_xor(lpart[r], msk, 64);

  // ---- merge pairs (qh,kh=0)+(qh,kh=1) via LDS ----
  float* sOw = (float*)(arena + wv * 4352);      // [16][68] f32
  #pragma unroll
  for (int dt = 0; dt < 4; ++dt)
    #pragma unroll
    for (int r = 0; r < 4; ++r)
      sOw[(4 * g + r) * 68 + 16 * dt + cc] = O[dt][r];
  float* sML = (float*)(arena + 22528);          // [w][2][16]
  if (cc == 0) {
    #pragma unroll
    for (int r = 0; r < 4; ++r) {
      sML[wv * 32 + (4 * g + r)] = mrun[r];
      sML[wv * 32 + 16 + (4 * g + r)] = lpart[r];
    }
  }
  __syncthreads();

  // 256 threads cover 32 rows x 64 cols, 8 cols/thread
  const int ii = tid >> 3;            // 0..31
  const int ii_l = ii & 15;
  const int w0 = (ii >> 4) * 2, w1 = w0 + 1;
  const int c0 = (tid & 7) * 8;
  const float m0 = sML[w0 * 32 + ii_l], l0 = sML[w0 * 32 + 16 + ii_l];
  const float m1 = sML[w1 * 32 + ii_l], l1 = sML[w1 * 32 + 16 + ii_l];
  const float M = fmaxf(m0, m1);
  const float f0 = __expf(m0 - M), f1 = __expf(m1 - M);
  const float rinv = 1.0f / (f0 * l0 + f1 * l1);
  const float* sO0 = (const float*)(arena + w0 * 4352);
  const float* sO1 = (const float*)(arena + w1 * 4352);
  short* dst = ctxb + (size_t)((blockIdx.x * 32 + ii) * BB + b) * EE + hoff + c0;
  #pragma unroll
  for (int jj = 0; jj < 8; ++jj) {
    const float val = (f0 * sO0[ii_l * 68 + c0 + jj] + f1 * sO1[ii_l * 68 + c0 + jj]) * rinv;
    dst[jj] = f2bf(val);
  }
}

// ---------------------------------------------------------------------------
extern "C" void kernel_launch(void* const* d_in, const int* in_sizes, int n_in,
                              void* d_out, int out_size, void* d_ws, size_t ws_size,
                              hipStream_t stream) {
  const float* x      = (const float*)d_in[0];
  const float* pos    = (const float*)d_in[1];
  const float* in_w   = (const float*)d_in[2];
  const float* in_b   = (const float*)d_in[3];
  const float* pos_w  = (const float*)d_in[4];
  const float* pos_b  = (const float*)d_in[5];
  const float* out_w  = (const float*)d_in[6];
  const float* out_b  = (const float*)d_in[7];
  const float* r_w    = (const float*)d_in[8];
  const float* r_r    = (const float*)d_in[9];
  float* out = (float*)d_out;

  const size_t M1 = 1024 * 1024;
  short* xb    = (short*)d_ws;        // 2M
  short* inwb  = xb    + 2 * M1;      // 3M
  short* posb  = inwb  + 3 * M1;      // 2M (2048 rows, row 2047 zeroed)
  short* poswb = posb  + 2 * M1;      // 1M
  short* outwb = poswb + 1 * M1;      // 1M
  short* qkvb  = outwb + 1 * M1;      // 6M
  short* pb    = qkvb  + 6 * M1;      // 2M
  short* ctxb  = pb    + 2 * M1;      // 2M
  short* vTb   = ctxb  + 2 * M1;      // 2M  (B*H*64*1024)

  cvt_all<<<dim3(4608), dim3(256), 0, stream>>>(
      x, in_w, pos, pos_w, out_w, xb, inwb, posb, poswb, outwb);

  gemm_bf16_mfma<1><<<dim3(E3 / GBN, TB / GBM), dim3(256), 0, stream>>>(
      xb, inwb, in_b, qkvb, TB, E3, EE);

  gemm_bf16_mfma<1><<<dim3(EE / GBN, 2048 / GBM), dim3(256), 0, stream>>>(
      posb, poswb, pos_b, pb, 2048, EE, EE);

  transpose_v<<<dim3(TT / 64, BB * HH), dim3(256), 0, stream>>>(qkvb, vTb);

  rel_attn_mfma7<<<dim3(TT / 32, BB * HH), dim3(256), 0, stream>>>(
      qkvb, pb, vTb, r_w, r_r, ctxb);

  gemm_bf16_mfma<0><<<dim3(EE / GBN, TB / GBM), dim3(256), 0, stream>>>(
      ctxb, outwb, out_b, out, TB, EE, EE);
}

// Round 11
// 134.604 us; speedup vs baseline: 1.4341x; 1.4341x over previous
//
#include <hip/hip_runtime.h>
#include <hip/hip_bf16.h>

// Problem constants: T=1024, B=2, E=1024, H=16, D=64, R=2*T-1
#define TT 1024
#define BB 2
#define EE 1024
#define HH 16
#define DD 64
#define RR 2047
#define TB (TT * BB)   // 2048
#define E3 (3 * EE)    // 3072

#define AS1 __attribute__((address_space(1)))
#define AS3 __attribute__((address_space(3)))

typedef __attribute__((ext_vector_type(4))) float f32x4;
typedef __attribute__((ext_vector_type(8))) short s16x8;

static __device__ __forceinline__ short f2bf(float x) {
  unsigned u = __builtin_bit_cast(unsigned, x);
  unsigned r = (u + 0x7FFFu + ((u >> 16) & 1u)) >> 16;
  return (short)r;
}
static __device__ __forceinline__ float bf2f(short x) {
  unsigned u = ((unsigned)(unsigned short)x) << 16;
  return __builtin_bit_cast(float, u);
}
static __device__ __forceinline__ float bperm(int idx, float v) {
  return __builtin_bit_cast(float,
      __builtin_amdgcn_ds_bpermute(idx, __builtin_bit_cast(int, v)));
}

// ---------------------------------------------------------------------------
// Fused fp32 -> bf16 convert for all 5 tensors (one launch).
// ---------------------------------------------------------------------------
__global__ __launch_bounds__(256) void cvt_all(
    const float* __restrict__ x, const float* __restrict__ in_w,
    const float* __restrict__ pos, const float* __restrict__ pos_w,
    const float* __restrict__ out_w,
    short* __restrict__ xb, short* __restrict__ inwb, short* __restrict__ posb,
    short* __restrict__ poswb, short* __restrict__ outwb) {
  const long M1 = 1 << 20;
  long off = (long)(blockIdx.x * 256 + threadIdx.x) * 8;
  const float* src; short* dst; long nsrc;
  if (off < 2 * M1)      { src = x;     dst = xb;    nsrc = 2 * M1; }
  else if (off < 5 * M1) { off -= 2 * M1; src = in_w;  dst = inwb;  nsrc = 3 * M1; }
  else if (off < 7 * M1) { off -= 5 * M1; src = pos;   dst = posb;  nsrc = (long)RR * EE; }
  else if (off < 8 * M1) { off -= 7 * M1; src = pos_w; dst = poswb; nsrc = M1; }
  else                   { off -= 8 * M1; src = out_w; dst = outwb; nsrc = M1; }
  s16x8 o;
  if (off + 8 <= nsrc) {
    f32x4 a = *(const f32x4*)&src[off];
    f32x4 c = *(const f32x4*)&src[off + 4];
    #pragma unroll
    for (int j = 0; j < 4; ++j) { o[j] = f2bf(a[j]); o[4 + j] = f2bf(c[j]); }
  } else {
    #pragma unroll
    for (int j = 0; j < 8; ++j) o[j] = 0;
  }
  *(s16x8*)&dst[off] = o;
}

// ---------------------------------------------------------------------------
// bf16 MFMA GEMM (m97 structure): C[M,N] = A[M,K] @ W[N,K]^T + bias[N]
// ---------------------------------------------------------------------------
#define GBM 128
#define GBN 128
#define GBK 32

template <int OUT_BF16>
__global__ __launch_bounds__(256) void gemm_bf16_mfma(
    const short* __restrict__ A, const short* __restrict__ W,
    const float* __restrict__ bias, void* __restrict__ Cout,
    int M, int N, int K) {
  __shared__ __align__(16) short lA[2][GBM * GBK];
  __shared__ __align__(16) short lB[2][GBN * GBK];

  const int tid = threadIdx.x;
  const int lane = tid & 63;
  const int wv = tid >> 6;
  const int g = lane >> 4, cc = lane & 15;
  const int wr = wv >> 1, wc = wv & 1;
  const int m0 = blockIdx.y * GBM, n0 = blockIdx.x * GBN;

  f32x4 acc[4][4];
  #pragma unroll
  for (int i = 0; i < 4; ++i)
    #pragma unroll
    for (int j = 0; j < 4; ++j) acc[i][j] = (f32x4){0.f, 0.f, 0.f, 0.f};

#define STAGE_TILE(kk_, buf_)                                                  \
  {                                                                            \
    _Pragma("unroll")                                                          \
    for (int s = 0; s < 2; ++s) {                                              \
      int c = s * 256 + tid;                                                   \
      int row = c >> 2, slot = c & 3;                                          \
      int k8 = slot ^ (row & 3);                                               \
      __builtin_amdgcn_global_load_lds(                                        \
          (const AS1 void*)(A + (size_t)(m0 + row) * K + (kk_) + k8 * 8),      \
          (AS3 void*)&lA[buf_][c * 8], 16, 0, 0);                              \
      __builtin_amdgcn_global_load_lds(                                        \
          (const AS1 void*)(W + (size_t)(n0 + row) * K + (kk_) + k8 * 8),      \
          (AS3 void*)&lB[buf_][c * 8], 16, 0, 0);                              \
    }                                                                          \
  }

  int cur = 0;
  const int nt = K / GBK;
  STAGE_TILE(0, 0);

  #pragma unroll 1
  for (int t = 0; t < nt; ++t) {
    __syncthreads();
    if (t + 1 < nt) STAGE_TILE((t + 1) * GBK, cur ^ 1);

    s16x8 af[4], bf[4];
    #pragma unroll
    for (int mt = 0; mt < 4; ++mt) {
      int row = 64 * wr + 16 * mt + cc;
      af[mt] = *(const s16x8*)&lA[cur][row * GBK + ((g ^ (row & 3)) * 8)];
    }
    #pragma unroll
    for (int ntc = 0; ntc < 4; ++ntc) {
      int col = 64 * wc + 16 * ntc + cc;
      bf[ntc] = *(const s16x8*)&lB[cur][col * GBK + ((g ^ (col & 3)) * 8)];
    }
    #pragma unroll
    for (int mt = 0; mt < 4; ++mt)
      #pragma unroll
      for (int ntc = 0; ntc < 4; ++ntc)
        acc[mt][ntc] = __builtin_amdgcn_mfma_f32_16x16x32_bf16(
            af[mt], bf[ntc], acc[mt][ntc], 0, 0, 0);
    cur ^= 1;
  }
#undef STAGE_TILE

  #pragma unroll
  for (int ntc = 0; ntc < 4; ++ntc) {
    int col = n0 + 64 * wc + 16 * ntc + cc;
    float bv = bias[col];
    #pragma unroll
    for (int mt = 0; mt < 4; ++mt)
      #pragma unroll
      for (int r = 0; r < 4; ++r) {
        int rowg = m0 + 64 * wr + 16 * mt + 4 * g + r;
        float val = acc[mt][ntc][r] + bv;
        if (OUT_BF16)
          ((short*)Cout)[(size_t)rowg * N + col] = f2bf(val);
        else
          ((float*)Cout)[(size_t)rowg * N + col] = val;
      }
  }
}

// ---------------------------------------------------------------------------
// V transpose: qkvb V-part [key][(h,d)] -> vT [bh][d][key]   (bf16, 4 MB)
// ---------------------------------------------------------------------------
__global__ __launch_bounds__(256) void transpose_v(
    const short* __restrict__ qkvb, short* __restrict__ vT) {
  __shared__ short tile[64][72];
  const int tid = threadIdx.x;
  const int kt = blockIdx.x;
  const int bh = blockIdx.y;
  const int b = bh >> 4, h = bh & 15;
  const int j = tid >> 2;           // 0..63 local key
  const int cg = (tid & 3) * 16;    // d group
  const short* src = qkvb + (size_t)((kt * 64 + j) * BB + b) * E3 + 2 * EE + h * DD + cg;
  *(s16x8*)&tile[j][cg]     = *(const s16x8*)src;
  *(s16x8*)&tile[j][cg + 8] = *(const s16x8*)(src + 8);
  __syncthreads();
  short* dst = vT + (size_t)(bh * DD + j) * TT + kt * 64 + cg;
  s16x8 o0, o1;
  #pragma unroll
  for (int m = 0; m < 8; ++m) { o0[m] = tile[cg + m][j]; o1[m] = tile[cg + 8 + m][j]; }
  *(s16x8*)dst       = o0;
  *(s16x8*)(dst + 8) = o1;
}

// ---------------------------------------------------------------------------
// MFMA flash attention — m97-style staged structure.
//   512 blocks (XCD-bijective: bh = (bid&7)*4 + (bid>>7), qx = (bid>>3)&15),
//   512 thr = 8 waves = (qsub 0..3) x (ksub 0..1). Block owns 64 q-rows;
//   16 steps of 64 keys. Per step, K-tile (8KB), vT-tile (8KB), p-band
//   (128 rows, 16KB) staged DOUBLE-BUFFERED via global_load_lds with
//   chunk-XOR swizzle (pre-swizzled global source, linear LDS dest);
//   one __syncthreads per step (m97 pattern keeps stage(t+1) in flight
//   under compute(t) with zero VGPR cost).
//   Wave computes 16q x 32k: AC (LDS kf) + BD (LDS pf, bperm gather) +
//   defer-max online softmax + sPm roundtrip + PV (LDS vf).
//   Band: block rows gmin=64t-iq0+960 +[0,128); wave rel = 32ksub-16qsub+48
//         + 16ut + cc; gather usub = jj-ii+15 (verbatim from R9).
// LDS (76800 B): buf[2] x { K@0 8KB | V@8192 8KB | P@16384 16KB } = 65536;
//   sPm[w]=65536+w*1280 (10240); sML=75776 (1024).
//   Merge sO[w]=arena+w*4352 aliases bufs (barrier-protected).
// ---------------------------------------------------------------------------
__global__ __launch_bounds__(512, 4) void rel_attn_mfma8(
    const short* __restrict__ qkvb,  // [TB][3E] bf16
    const short* __restrict__ pb,    // [2048][E] bf16 (row 2047 zeroed)
    const short* __restrict__ vT,    // [BH][64][1024] bf16
    const float* __restrict__ rwb,   // [H*D]
    const float* __restrict__ rrb,   // [H*D]
    short* __restrict__ ctxb) {      // [TB][E] bf16
  __shared__ __align__(16) char arena[76800];

  const int tid = threadIdx.x;
  const int wv = tid >> 6;
  const int qsub = wv & 3, ksub = wv >> 2;
  const int lane = tid & 63;
  const int g = lane >> 4, cc = lane & 15;

  // XCD-bijective decode over 512 blocks: all 16 q-blocks of a bh on one XCD
  const int bid = blockIdx.x;
  const int bh = (bid & 7) * 4 + (bid >> 7);   // [0,32)
  const int qx = (bid >> 3) & 15;              // [0,16)
  const int iq0 = qx * 64;
  const int b = bh >> 4, h = bh & 15;
  const int hoff = h * DD;

  short* sPm = (short*)(arena + 65536 + wv * 1280);    // [16][40]

  // ---- Q fragments: q row = iq0 + 16*qsub + cc ----
  s16x8 qw[2], qr[2];
  #pragma unroll
  for (int kh = 0; kh < 2; ++kh) {
    const int d0 = 32 * kh + 8 * g;
    const short* qp = qkvb + (size_t)((iq0 + 16 * qsub + cc) * BB + b) * E3 + hoff + d0;
    const float* rw = rwb + hoff + d0;
    const float* rr = rrb + hoff + d0;
    s16x8 qv = *(const s16x8*)qp;
    #pragma unroll
    for (int j = 0; j < 8; ++j) {
      float q = bf2f(qv[j]);
      qw[kh][j] = f2bf((q + rw[j]) * 0.125f);
      qr[kh][j] = f2bf((q + rr[j]) * 0.125f);
    }
  }

  f32x4 O[4];
  #pragma unroll
  for (int dt = 0; dt < 4; ++dt) O[dt] = (f32x4){0.f, 0.f, 0.f, 0.f};
  float mrun[4], lpart[4];
  #pragma unroll
  for (int r = 0; r < 4; ++r) { mrun[r] = -1e30f; lpart[r] = 0.f; }

  // Stage one 64-key step into buffer at byte base bufb_.
  // thread c: row=c>>3, chunk c8=c&7; fetches global chunk c8^(row&7) ->
  // linear LDS chunk c8 (both-sides swizzle, rule #21).
#define STAGE(t_, bufb_)                                                       \
  {                                                                            \
    const int j0s = (t_) * 64;                                                 \
    const int gmins = j0s - iq0 + 960;                                         \
    const int row = tid >> 3, c8 = tid & 7;                                    \
    const int swz = (c8 ^ (row & 7)) * 8;                                      \
    __builtin_amdgcn_global_load_lds(                                          \
        (const AS1 void*)(qkvb + (size_t)((j0s + row) * BB + b) * E3 + EE + hoff + swz), \
        (AS3 void*)((bufb_) + tid * 16), 16, 0, 0);                            \
    __builtin_amdgcn_global_load_lds(                                          \
        (const AS1 void*)(vT + (size_t)(bh * DD + row) * TT + j0s + swz),      \
        (AS3 void*)((bufb_) + 8192 + tid * 16), 16, 0, 0);                     \
    _Pragma("unroll")                                                          \
    for (int s2 = 0; s2 < 2; ++s2) {                                           \
      const int c2 = tid + 512 * s2;                                           \
      const int prow = c2 >> 3, pc8 = c2 & 7;                                  \
      const int pswz = (pc8 ^ (prow & 7)) * 8;                                 \
      __builtin_amdgcn_global_load_lds(                                        \
          (const AS1 void*)(pb + (size_t)(gmins + prow) * EE + hoff + pswz),   \
          (AS3 void*)((bufb_) + 16384 + c2 * 16), 16, 0, 0);                   \
    }                                                                          \
  }

  int cur = 0;
  STAGE(0, arena);

  #pragma unroll 1
  for (int t = 0; t < 16; ++t) {
    __syncthreads();   // stage(t) landed; buf[cur^1] free for stage(t+1)
    char* bufc = arena + cur * 32768;
    if (t + 1 < 16) STAGE(t + 1, arena + (cur ^ 1) * 32768);

    short* ldsK = (short*)bufc;              // [64 keys][64 d], swizzled
    short* ldsV = (short*)(bufc + 8192);     // [64 d][64 keys], swizzled
    short* ldsP = (short*)(bufc + 16384);    // [128 band rows][64 d], swizzled

    // ---- K fragments ----
    s16x8 kf[2][2];
    #pragma unroll
    for (int ct = 0; ct < 2; ++ct)
      #pragma unroll
      for (int kh = 0; kh < 2; ++kh) {
        const int row = 32 * ksub + 16 * ct + cc;
        kf[ct][kh] = *(const s16x8*)&ldsK[row * 64 + (((g + 4 * kh) ^ (row & 7)) * 8)];
      }

    // ---- AC: S[ct] = qw . K^T ----
    f32x4 S[2];
    #pragma unroll
    for (int ct = 0; ct < 2; ++ct) {
      S[ct] = (f32x4){0.f, 0.f, 0.f, 0.f};
      #pragma unroll
      for (int kh = 0; kh < 2; ++kh)
        S[ct] = __builtin_amdgcn_mfma_f32_16x16x32_bf16(qw[kh], kf[ct][kh], S[ct], 0, 0, 0);
    }

    // ---- BD: Btilde = qr . band^T (3 ut tiles from LDS band) ----
    const int bbase = 32 * ksub - 16 * qsub + 48;   // wave band offset
    f32x4 bt[3];
    #pragma unroll
    for (int ut = 0; ut < 3; ++ut) {
      const int rel = bbase + 16 * ut + cc;         // [0,127]
      bt[ut] = (f32x4){0.f, 0.f, 0.f, 0.f};
      #pragma unroll
      for (int kh = 0; kh < 2; ++kh) {
        s16x8 pf = *(const s16x8*)&ldsP[rel * 64 + (((g + 4 * kh) ^ (rel & 7)) * 8)];
        bt[ut] = __builtin_amdgcn_mfma_f32_16x16x32_bf16(qr[kh], pf, bt[ut], 0, 0, 0);
      }
    }
    // gather: S[ct][r] += Btilde[ii=4g+r][usub=16ct+cc+15-ii] via bpermute
    #pragma unroll
    for (int r = 0; r < 4; ++r) {
      const int usub = cc + 15 - 4 * g - r;            // 0..30
      const int idx = ((lane & 48) | (usub & 15)) << 2;
      const float va = bperm(idx, bt[0][r]);
      const float vb = bperm(idx, bt[1][r]);
      const float vc = bperm(idx, bt[2][r]);
      const bool hi = usub >= 16;
      S[0][r] += hi ? vb : va;
      S[1][r] += hi ? vc : vb;
    }

    // ---- defer-max online softmax (exact) ----
    float mx[4];
    #pragma unroll
    for (int r = 0; r < 4; ++r) mx[r] = fmaxf(S[0][r], S[1][r]);
    const bool need = (mx[0] > mrun[0]) || (mx[1] > mrun[1]) ||
                      (mx[2] > mrun[2]) || (mx[3] > mrun[3]);
    if (__any(need)) {
      #pragma unroll
      for (int msk = 1; msk < 16; msk <<= 1)
        #pragma unroll
        for (int r = 0; r < 4; ++r) mx[r] = fmaxf(mx[r], __shfl_xor(mx[r], msk, 64));
      #pragma unroll
      for (int r = 0; r < 4; ++r) {
        const float mn = fmaxf(mrun[r], mx[r]);
        const float f = __expf(mrun[r] - mn);
        mrun[r] = mn;
        lpart[r] *= f;
        #pragma unroll
        for (int dt = 0; dt < 4; ++dt) O[dt][r] *= f;
      }
    }
    #pragma unroll
    for (int r = 0; r < 4; ++r) {
      S[0][r] = __expf(S[0][r] - mrun[r]);
      S[1][r] = __expf(S[1][r] - mrun[r]);
      lpart[r] += S[0][r] + S[1][r];
    }

    // ---- P to A-fragment layout via wave-private LDS ----
    #pragma unroll
    for (int ct = 0; ct < 2; ++ct)
      #pragma unroll
      for (int r = 0; r < 4; ++r)
        sPm[(4 * g + r) * 40 + 16 * ct + cc] = f2bf(S[ct][r]);

    s16x8 pa = *(const s16x8*)&sPm[cc * 40 + 8 * g];

    // ---- V^T fragments from LDS + PV ----
    #pragma unroll
    for (int dt = 0; dt < 4; ++dt) {
      const int row = 16 * dt + cc;
      s16x8 vf = *(const s16x8*)&ldsV[row * 64 + (((4 * ksub + g) ^ (row & 7)) * 8)];
      O[dt] = __builtin_amdgcn_mfma_f32_16x16x32_bf16(pa, vf, O[dt], 0, 0, 0);
    }
    cur ^= 1;
  }
#undef STAGE

  // ---- final 16-lane sum reduce of lpart ----
  #pragma unroll
  for (int msk = 1; msk < 16; msk <<= 1)
    #pragma unroll
    for (int r = 0; r < 4; ++r) lpart[r] += __shfl_xor(lpart[r], msk, 64);

  __syncthreads();   // all LDS reads done before sO overwrites buffers

  // ---- merge pairs (qsub, ksub=0)+(qsub, ksub=1) via LDS ----
  float* sOw = (float*)(arena + wv * 4352);      // [16][68] f32
  #pragma unroll
  for (int dt = 0; dt < 4; ++dt)
    #pragma unroll
    for (int r = 0; r < 4; ++r)
      sOw[(4 * g + r) * 68 + 16 * dt + cc] = O[dt][r];
  float* sML = (float*)(arena + 75776);          // [w][2][16]
  if (cc == 0) {
    #pragma unroll
    for (int r = 0; r < 4; ++r) {
      sML[wv * 32 + (4 * g + r)] = mrun[r];
      sML[wv * 32 + 16 + (4 * g + r)] = lpart[r];
    }
  }
  __syncthreads();

  // 512 threads cover 64 rows x 64 cols, 8 cols/thread
  const int ii = tid >> 3;            // 0..63
  const int ii_l = ii & 15;
  const int w0 = ii >> 4, w1 = w0 + 4;
  const int c0 = (tid & 7) * 8;
  const float m0 = sML[w0 * 32 + ii_l], l0 = sML[w0 * 32 + 16 + ii_l];
  const float m1 = sML[w1 * 32 + ii_l], l1 = sML[w1 * 32 + 16 + ii_l];
  const float M = fmaxf(m0, m1);
  const float f0 = __expf(m0 - M), f1 = __expf(m1 - M);
  const float rinv = 1.0f / (f0 * l0 + f1 * l1);
  const float* sO0 = (const float*)(arena + w0 * 4352);
  const float* sO1 = (const float*)(arena + w1 * 4352);
  s16x8 ov;
  #pragma unroll
  for (int jj = 0; jj < 8; ++jj) {
    const float val = (f0 * sO0[ii_l * 68 + c0 + jj] + f1 * sO1[ii_l * 68 + c0 + jj]) * rinv;
    ov[jj] = f2bf(val);
  }
  *(s16x8*)(ctxb + (size_t)((iq0 + ii) * BB + b) * EE + hoff + c0) = ov;
}

// ---------------------------------------------------------------------------
extern "C" void kernel_launch(void* const* d_in, const int* in_sizes, int n_in,
                              void* d_out, int out_size, void* d_ws, size_t ws_size,
                              hipStream_t stream) {
  const float* x      = (const float*)d_in[0];
  const float* pos    = (const float*)d_in[1];
  const float* in_w   = (const float*)d_in[2];
  const float* in_b   = (const float*)d_in[3];
  const float* pos_w  = (const float*)d_in[4];
  const float* pos_b  = (const float*)d_in[5];
  const float* out_w  = (const float*)d_in[6];
  const float* out_b  = (const float*)d_in[7];
  const float* r_w    = (const float*)d_in[8];
  const float* r_r    = (const float*)d_in[9];
  float* out = (float*)d_out;

  const size_t M1 = 1024 * 1024;
  short* xb    = (short*)d_ws;        // 2M
  short* inwb  = xb    + 2 * M1;      // 3M
  short* posb  = inwb  + 3 * M1;      // 2M (2048 rows, row 2047 zeroed)
  short* poswb = posb  + 2 * M1;      // 1M
  short* outwb = poswb + 1 * M1;      // 1M
  short* qkvb  = outwb + 1 * M1;      // 6M
  short* pb    = qkvb  + 6 * M1;      // 2M
  short* ctxb  = pb    + 2 * M1;      // 2M
  short* vTb   = ctxb  + 2 * M1;      // 2M  (B*H*64*1024)

  cvt_all<<<dim3(4608), dim3(256), 0, stream>>>(
      x, in_w, pos, pos_w, out_w, xb, inwb, posb, poswb, outwb);

  gemm_bf16_mfma<1><<<dim3(E3 / GBN, TB / GBM), dim3(256), 0, stream>>>(
      xb, inwb, in_b, qkvb, TB, E3, EE);

  gemm_bf16_mfma<1><<<dim3(EE / GBN, 2048 / GBM), dim3(256), 0, stream>>>(
      posb, poswb, pos_b, pb, 2048, EE, EE);

  transpose_v<<<dim3(TT / 64, BB * HH), dim3(256), 0, stream>>>(qkvb, vTb);

  rel_attn_mfma8<<<dim3(512), dim3(512), 0, stream>>>(
      qkvb, pb, vTb, r_w, r_r, ctxb);

  gemm_bf16_mfma<0><<<dim3(EE / GBN, TB / GBM), dim3(256), 0, stream>>>(
      ctxb, outwb, out_b, out, TB, EE, EE);
}

// Round 12
// 109.514 us; speedup vs baseline: 1.7627x; 1.2291x over previous
//
#include <hip/hip_runtime.h>
#include <hip/hip_bf16.h>

// Problem constants: T=1024, B=2, E=1024, H=16, D=64, R=2*T-1
#define TT 1024
#define BB 2
#define EE 1024
#define HH 16
#define DD 64
#define RR 2047
#define TB (TT * BB)   // 2048
#define E3 (3 * EE)    // 3072

#define AS1 __attribute__((address_space(1)))
#define AS3 __attribute__((address_space(3)))

typedef __attribute__((ext_vector_type(4))) float f32x4;
typedef __attribute__((ext_vector_type(8))) short s16x8;

static __device__ __forceinline__ short f2bf(float x) {
  unsigned u = __builtin_bit_cast(unsigned, x);
  unsigned r = (u + 0x7FFFu + ((u >> 16) & 1u)) >> 16;
  return (short)r;
}
static __device__ __forceinline__ float bf2f(short x) {
  unsigned u = ((unsigned)(unsigned short)x) << 16;
  return __builtin_bit_cast(float, u);
}
static __device__ __forceinline__ float bperm(int idx, float v) {
  return __builtin_bit_cast(float,
      __builtin_amdgcn_ds_bpermute(idx, __builtin_bit_cast(int, v)));
}

// ---------------------------------------------------------------------------
// Fused fp32 -> bf16 convert for all 5 tensors (one launch).
// ---------------------------------------------------------------------------
__global__ __launch_bounds__(256) void cvt_all(
    const float* __restrict__ x, const float* __restrict__ in_w,
    const float* __restrict__ pos, const float* __restrict__ pos_w,
    const float* __restrict__ out_w,
    short* __restrict__ xb, short* __restrict__ inwb, short* __restrict__ posb,
    short* __restrict__ poswb, short* __restrict__ outwb) {
  const long M1 = 1 << 20;
  long off = (long)(blockIdx.x * 256 + threadIdx.x) * 8;
  const float* src; short* dst; long nsrc;
  if (off < 2 * M1)      { src = x;     dst = xb;    nsrc = 2 * M1; }
  else if (off < 5 * M1) { off -= 2 * M1; src = in_w;  dst = inwb;  nsrc = 3 * M1; }
  else if (off < 7 * M1) { off -= 5 * M1; src = pos;   dst = posb;  nsrc = (long)RR * EE; }
  else if (off < 8 * M1) { off -= 7 * M1; src = pos_w; dst = poswb; nsrc = M1; }
  else                   { off -= 8 * M1; src = out_w; dst = outwb; nsrc = M1; }
  s16x8 o;
  if (off + 8 <= nsrc) {
    f32x4 a = *(const f32x4*)&src[off];
    f32x4 c = *(const f32x4*)&src[off + 4];
    #pragma unroll
    for (int j = 0; j < 4; ++j) { o[j] = f2bf(a[j]); o[4 + j] = f2bf(c[j]); }
  } else {
    #pragma unroll
    for (int j = 0; j < 8; ++j) o[j] = 0;
  }
  *(s16x8*)&dst[off] = o;
}

// ---------------------------------------------------------------------------
// bf16 MFMA GEMM body (m97 structure), tile-parameterized.
//   C[M,N] = A[M,K] @ W[N,K]^T + bias[N]; 256 threads; waves WR x WC.
//   Single call site per kernel (shared LDS not duplicated).
// ---------------------------------------------------------------------------
#define GBK 32

template <int BM, int BN, int WR, int WC, int OUT_BF16>
__device__ __forceinline__ void gemm_body(
    const short* __restrict__ A, const short* __restrict__ W,
    const float* __restrict__ bias, void* __restrict__ Cout,
    int M, int N, int K, int m0, int n0) {
  __shared__ __align__(16) short lA[2][BM * GBK];
  __shared__ __align__(16) short lB[2][BN * GBK];
  constexpr int MT = BM / WR / 16;
  constexpr int NT = BN / WC / 16;
  constexpr int ACH = BM * 4 / 256;   // A chunk-loop iters
  constexpr int BCH = BN * 4 / 256;   // B chunk-loop iters

  const int tid = threadIdx.x;
  const int lane = tid & 63;
  const int wv = tid >> 6;
  const int g = lane >> 4, cc = lane & 15;
  const int wr = wv / WC, wc = wv % WC;

  f32x4 acc[MT][NT];
  #pragma unroll
  for (int i = 0; i < MT; ++i)
    #pragma unroll
    for (int j = 0; j < NT; ++j) acc[i][j] = (f32x4){0.f, 0.f, 0.f, 0.f};

  auto stage = [&](int kk, int buf) {
    #pragma unroll
    for (int s = 0; s < ACH; ++s) {
      int c = s * 256 + tid;
      int row = c >> 2, slot = c & 3;
      int k8 = slot ^ (row & 3);
      __builtin_amdgcn_global_load_lds(
          (const AS1 void*)(A + (size_t)(m0 + row) * K + kk + k8 * 8),
          (AS3 void*)&lA[buf][c * 8], 16, 0, 0);
    }
    #pragma unroll
    for (int s = 0; s < BCH; ++s) {
      int c = s * 256 + tid;
      int row = c >> 2, slot = c & 3;
      int k8 = slot ^ (row & 3);
      __builtin_amdgcn_global_load_lds(
          (const AS1 void*)(W + (size_t)(n0 + row) * K + kk + k8 * 8),
          (AS3 void*)&lB[buf][c * 8], 16, 0, 0);
    }
  };

  int cur = 0;
  const int nt = K / GBK;
  stage(0, 0);

  #pragma unroll 1
  for (int t = 0; t < nt; ++t) {
    __syncthreads();
    if (t + 1 < nt) stage((t + 1) * GBK, cur ^ 1);

    s16x8 af[MT], bf[NT];
    #pragma unroll
    for (int mt = 0; mt < MT; ++mt) {
      int row = (BM / WR) * wr + 16 * mt + cc;
      af[mt] = *(const s16x8*)&lA[cur][row * GBK + ((g ^ (row & 3)) * 8)];
    }
    #pragma unroll
    for (int ntc = 0; ntc < NT; ++ntc) {
      int col = (BN / WC) * wc + 16 * ntc + cc;
      bf[ntc] = *(const s16x8*)&lB[cur][col * GBK + ((g ^ (col & 3)) * 8)];
    }
    #pragma unroll
    for (int mt = 0; mt < MT; ++mt)
      #pragma unroll
      for (int ntc = 0; ntc < NT; ++ntc)
        acc[mt][ntc] = __builtin_amdgcn_mfma_f32_16x16x32_bf16(
            af[mt], bf[ntc], acc[mt][ntc], 0, 0, 0);
    cur ^= 1;
  }

  #pragma unroll
  for (int ntc = 0; ntc < NT; ++ntc) {
    int col = n0 + (BN / WC) * wc + 16 * ntc + cc;
    float bv = bias[col - n0 + n0];     // = bias[col]
    bv = bias[col];
    #pragma unroll
    for (int mt = 0; mt < MT; ++mt)
      #pragma unroll
      for (int r = 0; r < 4; ++r) {
        int rowg = m0 + (BM / WR) * wr + 16 * mt + 4 * g + r;
        float val = acc[mt][ntc][r] + bv;
        if (OUT_BF16)
          ((short*)Cout)[(size_t)rowg * N + col] = f2bf(val);
        else
          ((float*)Cout)[(size_t)rowg * N + col] = val;
      }
  }
}

// Fused qkv-proj (384 blocks) + pos-proj (128 blocks): 512 blocks, even fill.
__global__ __launch_bounds__(256) void gemm_qkv_pos(
    const short* __restrict__ xb, const short* __restrict__ inwb,
    const float* __restrict__ in_b, short* __restrict__ qkvb,
    const short* __restrict__ posb, const short* __restrict__ poswb,
    const float* __restrict__ pos_b, short* __restrict__ pb) {
  const int bid = blockIdx.x;
  const short *A, *W; const float* bias; short* C; int N, m0, n0;
  if (bid < 384) {                // qkv: [2048 x 3072 x 1024]
    A = xb; W = inwb; bias = in_b; C = qkvb; N = E3;
    n0 = (bid % 24) * 128; m0 = (bid / 24) * 128;
  } else {                        // pos: [2048 x 1024 x 1024]
    const int i = bid - 384;
    A = posb; W = poswb; bias = pos_b; C = pb; N = EE;
    n0 = (i % 8) * 128; m0 = (i / 8) * 128;
  }
  gemm_body<128, 128, 2, 2, 1>(A, W, bias, C, TB, N, EE, m0, n0);
}

// out-proj: 128x64 tiles -> 256 blocks (every CU busy), fp32 out.
__global__ __launch_bounds__(256) void gemm_out(
    const short* __restrict__ ctxb, const short* __restrict__ outwb,
    const float* __restrict__ out_b, float* __restrict__ out) {
  gemm_body<128, 64, 4, 1, 0>(ctxb, outwb, out_b, out, TB, EE, EE,
                              blockIdx.y * 128, blockIdx.x * 64);
}

// ---------------------------------------------------------------------------
// V transpose: qkvb V-part [key][(h,d)] -> vT [bh][d][key]   (bf16, 4 MB)
// ---------------------------------------------------------------------------
__global__ __launch_bounds__(256) void transpose_v(
    const short* __restrict__ qkvb, short* __restrict__ vT) {
  __shared__ short tile[64][72];
  const int tid = threadIdx.x;
  const int kt = blockIdx.x;
  const int bh = blockIdx.y;
  const int b = bh >> 4, h = bh & 15;
  const int j = tid >> 2;           // 0..63 local key
  const int cg = (tid & 3) * 16;    // d group
  const short* src = qkvb + (size_t)((kt * 64 + j) * BB + b) * E3 + 2 * EE + h * DD + cg;
  *(s16x8*)&tile[j][cg]     = *(const s16x8*)src;
  *(s16x8*)&tile[j][cg + 8] = *(const s16x8*)(src + 8);
  __syncthreads();
  short* dst = vT + (size_t)(bh * DD + j) * TT + kt * 64 + cg;
  s16x8 o0, o1;
  #pragma unroll
  for (int m = 0; m < 8; ++m) { o0[m] = tile[cg + m][j]; o1[m] = tile[cg + 8 + m][j]; }
  *(s16x8*)dst       = o0;
  *(s16x8*)(dst + 8) = o1;
}

// ---------------------------------------------------------------------------
// MFMA flash attention — m97-style staged structure (unchanged from R11).
// ---------------------------------------------------------------------------
__global__ __launch_bounds__(512, 4) void rel_attn_mfma8(
    const short* __restrict__ qkvb,  // [TB][3E] bf16
    const short* __restrict__ pb,    // [2048][E] bf16 (row 2047 zeroed)
    const short* __restrict__ vT,    // [BH][64][1024] bf16
    const float* __restrict__ rwb,   // [H*D]
    const float* __restrict__ rrb,   // [H*D]
    short* __restrict__ ctxb) {      // [TB][E] bf16
  __shared__ __align__(16) char arena[76800];

  const int tid = threadIdx.x;
  const int wv = tid >> 6;
  const int qsub = wv & 3, ksub = wv >> 2;
  const int lane = tid & 63;
  const int g = lane >> 4, cc = lane & 15;

  // XCD-bijective decode over 512 blocks: all 16 q-blocks of a bh on one XCD
  const int bid = blockIdx.x;
  const int bh = (bid & 7) * 4 + (bid >> 7);   // [0,32)
  const int qx = (bid >> 3) & 15;              // [0,16)
  const int iq0 = qx * 64;
  const int b = bh >> 4, h = bh & 15;
  const int hoff = h * DD;

  short* sPm = (short*)(arena + 65536 + wv * 1280);    // [16][40]

  // ---- Q fragments: q row = iq0 + 16*qsub + cc ----
  s16x8 qw[2], qr[2];
  #pragma unroll
  for (int kh = 0; kh < 2; ++kh) {
    const int d0 = 32 * kh + 8 * g;
    const short* qp = qkvb + (size_t)((iq0 + 16 * qsub + cc) * BB + b) * E3 + hoff + d0;
    const float* rw = rwb + hoff + d0;
    const float* rr = rrb + hoff + d0;
    s16x8 qv = *(const s16x8*)qp;
    #pragma unroll
    for (int j = 0; j < 8; ++j) {
      float q = bf2f(qv[j]);
      qw[kh][j] = f2bf((q + rw[j]) * 0.125f);
      qr[kh][j] = f2bf((q + rr[j]) * 0.125f);
    }
  }

  f32x4 O[4];
  #pragma unroll
  for (int dt = 0; dt < 4; ++dt) O[dt] = (f32x4){0.f, 0.f, 0.f, 0.f};
  float mrun[4], lpart[4];
  #pragma unroll
  for (int r = 0; r < 4; ++r) { mrun[r] = -1e30f; lpart[r] = 0.f; }

#define STAGE(t_, bufb_)                                                       \
  {                                                                            \
    const int j0s = (t_) * 64;                                                 \
    const int gmins = j0s - iq0 + 960;                                         \
    const int row = tid >> 3, c8 = tid & 7;                                    \
    const int swz = (c8 ^ (row & 7)) * 8;                                      \
    __builtin_amdgcn_global_load_lds(                                          \
        (const AS1 void*)(qkvb + (size_t)((j0s + row) * BB + b) * E3 + EE + hoff + swz), \
        (AS3 void*)((bufb_) + tid * 16), 16, 0, 0);                            \
    __builtin_amdgcn_global_load_lds(                                          \
        (const AS1 void*)(vT + (size_t)(bh * DD + row) * TT + j0s + swz),      \
        (AS3 void*)((bufb_) + 8192 + tid * 16), 16, 0, 0);                     \
    _Pragma("unroll")                                                          \
    for (int s2 = 0; s2 < 2; ++s2) {                                           \
      const int c2 = tid + 512 * s2;                                           \
      const int prow = c2 >> 3, pc8 = c2 & 7;                                  \
      const int pswz = (pc8 ^ (prow & 7)) * 8;                                 \
      __builtin_amdgcn_global_load_lds(                                        \
          (const AS1 void*)(pb + (size_t)(gmins + prow) * EE + hoff + pswz),   \
          (AS3 void*)((bufb_) + 16384 + c2 * 16), 16, 0, 0);                   \
    }                                                                          \
  }

  int cur = 0;
  STAGE(0, arena);

  #pragma unroll 1
  for (int t = 0; t < 16; ++t) {
    __syncthreads();   // stage(t) landed; buf[cur^1] free for stage(t+1)
    char* bufc = arena + cur * 32768;
    if (t + 1 < 16) STAGE(t + 1, arena + (cur ^ 1) * 32768);

    short* ldsK = (short*)bufc;              // [64 keys][64 d], swizzled
    short* ldsV = (short*)(bufc + 8192);     // [64 d][64 keys], swizzled
    short* ldsP = (short*)(bufc + 16384);    // [128 band rows][64 d], swizzled

    // ---- K fragments ----
    s16x8 kf[2][2];
    #pragma unroll
    for (int ct = 0; ct < 2; ++ct)
      #pragma unroll
      for (int kh = 0; kh < 2; ++kh) {
        const int row = 32 * ksub + 16 * ct + cc;
        kf[ct][kh] = *(const s16x8*)&ldsK[row * 64 + (((g + 4 * kh) ^ (row & 7)) * 8)];
      }

    // ---- AC: S[ct] = qw . K^T ----
    f32x4 S[2];
    #pragma unroll
    for (int ct = 0; ct < 2; ++ct) {
      S[ct] = (f32x4){0.f, 0.f, 0.f, 0.f};
      #pragma unroll
      for (int kh = 0; kh < 2; ++kh)
        S[ct] = __builtin_amdgcn_mfma_f32_16x16x32_bf16(qw[kh], kf[ct][kh], S[ct], 0, 0, 0);
    }

    // ---- BD: Btilde = qr . band^T (3 ut tiles from LDS band) ----
    const int bbase = 32 * ksub - 16 * qsub + 48;   // wave band offset
    f32x4 bt[3];
    #pragma unroll
    for (int ut = 0; ut < 3; ++ut) {
      const int rel = bbase + 16 * ut + cc;         // [0,127]
      bt[ut] = (f32x4){0.f, 0.f, 0.f, 0.f};
      #pragma unroll
      for (int kh = 0; kh < 2; ++kh) {
        s16x8 pf = *(const s16x8*)&ldsP[rel * 64 + (((g + 4 * kh) ^ (rel & 7)) * 8)];
        bt[ut] = __builtin_amdgcn_mfma_f32_16x16x32_bf16(qr[kh], pf, bt[ut], 0, 0, 0);
      }
    }
    // gather: S[ct][r] += Btilde[ii=4g+r][usub=16ct+cc+15-ii] via bpermute
    #pragma unroll
    for (int r = 0; r < 4; ++r) {
      const int usub = cc + 15 - 4 * g - r;            // 0..30
      const int idx = ((lane & 48) | (usub & 15)) << 2;
      const float va = bperm(idx, bt[0][r]);
      const float vb = bperm(idx, bt[1][r]);
      const float vc = bperm(idx, bt[2][r]);
      const bool hi = usub >= 16;
      S[0][r] += hi ? vb : va;
      S[1][r] += hi ? vc : vb;
    }

    // ---- defer-max online softmax (exact) ----
    float mx[4];
    #pragma unroll
    for (int r = 0; r < 4; ++r) mx[r] = fmaxf(S[0][r], S[1][r]);
    const bool need = (mx[0] > mrun[0]) || (mx[1] > mrun[1]) ||
                      (mx[2] > mrun[2]) || (mx[3] > mrun[3]);
    if (__any(need)) {
      #pragma unroll
      for (int msk = 1; msk < 16; msk <<= 1)
        #pragma unroll
        for (int r = 0; r < 4; ++r) mx[r] = fmaxf(mx[r], __shfl_xor(mx[r], msk, 64));
      #pragma unroll
      for (int r = 0; r < 4; ++r) {
        const float mn = fmaxf(mrun[r], mx[r]);
        const float f = __expf(mrun[r] - mn);
        mrun[r] = mn;
        lpart[r] *= f;
        #pragma unroll
        for (int dt = 0; dt < 4; ++dt) O[dt][r] *= f;
      }
    }
    #pragma unroll
    for (int r = 0; r < 4; ++r) {
      S[0][r] = __expf(S[0][r] - mrun[r]);
      S[1][r] = __expf(S[1][r] - mrun[r]);
      lpart[r] += S[0][r] + S[1][r];
    }

    // ---- P to A-fragment layout via wave-private LDS ----
    #pragma unroll
    for (int ct = 0; ct < 2; ++ct)
      #pragma unroll
      for (int r = 0; r < 4; ++r)
        sPm[(4 * g + r) * 40 + 16 * ct + cc] = f2bf(S[ct][r]);

    s16x8 pa = *(const s16x8*)&sPm[cc * 40 + 8 * g];

    // ---- V^T fragments from LDS + PV ----
    #pragma unroll
    for (int dt = 0; dt < 4; ++dt) {
      const int row = 16 * dt + cc;
      s16x8 vf = *(const s16x8*)&ldsV[row * 64 + (((4 * ksub + g) ^ (row & 7)) * 8)];
      O[dt] = __builtin_amdgcn_mfma_f32_16x16x32_bf16(pa, vf, O[dt], 0, 0, 0);
    }
    cur ^= 1;
  }
#undef STAGE

  // ---- final 16-lane sum reduce of lpart ----
  #pragma unroll
  for (int msk = 1; msk < 16; msk <<= 1)
    #pragma unroll
    for (int r = 0; r < 4; ++r) lpart[r] += __shfl_xor(lpart[r], msk, 64);

  __syncthreads();   // all LDS reads done before sO overwrites buffers

  // ---- merge pairs (qsub, ksub=0)+(qsub, ksub=1) via LDS ----
  float* sOw = (float*)(arena + wv * 4352);      // [16][68] f32
  #pragma unroll
  for (int dt = 0; dt < 4; ++dt)
    #pragma unroll
    for (int r = 0; r < 4; ++r)
      sOw[(4 * g + r) * 68 + 16 * dt + cc] = O[dt][r];
  float* sML = (float*)(arena + 75776);          // [w][2][16]
  if (cc == 0) {
    #pragma unroll
    for (int r = 0; r < 4; ++r) {
      sML[wv * 32 + (4 * g + r)] = mrun[r];
      sML[wv * 32 + 16 + (4 * g + r)] = lpart[r];
    }
  }
  __syncthreads();

  // 512 threads cover 64 rows x 64 cols, 8 cols/thread
  const int ii = tid >> 3;            // 0..63
  const int ii_l = ii & 15;
  const int w0 = ii >> 4, w1 = w0 + 4;
  const int c0 = (tid & 7) * 8;
  const float m0 = sML[w0 * 32 + ii_l], l0 = sML[w0 * 32 + 16 + ii_l];
  const float m1 = sML[w1 * 32 + ii_l], l1 = sML[w1 * 32 + 16 + ii_l];
  const float M = fmaxf(m0, m1);
  const float f0 = __expf(m0 - M), f1 = __expf(m1 - M);
  const float rinv = 1.0f / (f0 * l0 + f1 * l1);
  const float* sO0 = (const float*)(arena + w0 * 4352);
  const float* sO1 = (const float*)(arena + w1 * 4352);
  s16x8 ov;
  #pragma unroll
  for (int jj = 0; jj < 8; ++jj) {
    const float val = (f0 * sO0[ii_l * 68 + c0 + jj] + f1 * sO1[ii_l * 68 + c0 + jj]) * rinv;
    ov[jj] = f2bf(val);
  }
  *(s16x8*)(ctxb + (size_t)((iq0 + ii) * BB + b) * EE + hoff + c0) = ov;
}

// ---------------------------------------------------------------------------
extern "C" void kernel_launch(void* const* d_in, const int* in_sizes, int n_in,
                              void* d_out, int out_size, void* d_ws, size_t ws_size,
                              hipStream_t stream) {
  const float* x      = (const float*)d_in[0];
  const float* pos    = (const float*)d_in[1];
  const float* in_w   = (const float*)d_in[2];
  const float* in_b   = (const float*)d_in[3];
  const float* pos_w  = (const float*)d_in[4];
  const float* pos_b  = (const float*)d_in[5];
  const float* out_w  = (const float*)d_in[6];
  const float* out_b  = (const float*)d_in[7];
  const float* r_w    = (const float*)d_in[8];
  const float* r_r    = (const float*)d_in[9];
  float* out = (float*)d_out;

  const size_t M1 = 1024 * 1024;
  short* xb    = (short*)d_ws;        // 2M
  short* inwb  = xb    + 2 * M1;      // 3M
  short* posb  = inwb  + 3 * M1;      // 2M (2048 rows, row 2047 zeroed)
  short* poswb = posb  + 2 * M1;      // 1M
  short* outwb = poswb + 1 * M1;      // 1M
  short* qkvb  = outwb + 1 * M1;      // 6M
  short* pb    = qkvb  + 6 * M1;      // 2M
  short* ctxb  = pb    + 2 * M1;      // 2M
  short* vTb   = ctxb  + 2 * M1;      // 2M  (B*H*64*1024)

  cvt_all<<<dim3(4608), dim3(256), 0, stream>>>(
      x, in_w, pos, pos_w, out_w, xb, inwb, posb, poswb, outwb);

  // fused qkv-proj + pos-proj: 512 blocks, even machine fill
  gemm_qkv_pos<<<dim3(512), dim3(256), 0, stream>>>(
      xb, inwb, in_b, qkvb, posb, poswb, pos_b, pb);

  transpose_v<<<dim3(TT / 64, BB * HH), dim3(256), 0, stream>>>(qkvb, vTb);

  rel_attn_mfma8<<<dim3(512), dim3(512), 0, stream>>>(
      qkvb, pb, vTb, r_w, r_r, ctxb);

  // out-proj: 128x64 tiles, 256 blocks
  gemm_out<<<dim3(EE / 64, TB / 128), dim3(256), 0, stream>>>(
      ctxb, outwb, out_b, out);
}